// Round 16
// baseline (87.132 us; speedup 1.0000x reference)
//
#include <hip/hip_runtime.h>
#include <cstdint>
#include <cstddef>

#define BATCH 8
#define FHh   32
#define FWw   256
#define NA    6
#define NANCH (FHh * FWw * NA)   // 49152
#define PRE_K 2000
#define POST_K 300
#define SEGS  192                // blocks per batch in k_gather
#define CAND_CAP 4096
#define BIN_LO 0x3E2Au           // bin(1/6): 2000th key's bin >= this
#define SH_BASE 0x3E00u          // small-hist base; covers [0x3E00, 0x4000)
#define SHBIN 512                // scores <= 1.0 -> bin <= 0x3F80 < 0x4000
#define RMAX_EP 20               // k_iou precomputes epochs [0,20); rest inline

typedef unsigned long long u64;

// -------- workspace layout (bytes); d_ws is 256 MiB — all regions disjoint ---
#define WS_SC   0                 // scores   1,572,864
#define WS_HIST 1572864           // raw 512-bin hist, 8*512*4 = 16,384
#define WS_CAND 4194304           // 8*192*256*8 = 3,145,728
#define WS_CNT  7340032           // 8*192*4 = 6,144
#define WS_PB   7602176           // pre_boxes 256,000
#define WS_PS   7858176           // pre_scores 64,000
#define WS_SUPP 8388608           // supp (rows < RMAX_EP*64, upper-tri written)

// ---------------- K0: zero the 16KB histogram (one block) --------------------
__global__ __launch_bounds__(1024) void k_zero(uint4* __restrict__ hist4) {
    hist4[threadIdx.x] = make_uint4(0u, 0u, 0u, 0u);   // 1024 x 16B = 16KB
}

// ---------------- K1: fused softmax + pruned 512-bin histogram ---------------
__global__ void k_softhist(const float* __restrict__ labels, float* __restrict__ scores,
                           unsigned int* __restrict__ hist) {
    int pos = blockIdx.x * blockDim.x + threadIdx.x;  // over BATCH*FH*FW
    if (pos >= BATCH * FHh * FWw) return;
    int b = pos / (FHh * FWw);
    const float2* in2 = (const float2*)(labels + (size_t)pos * NA);
    float v[NA];
    float2 p0 = in2[0], p1 = in2[1], p2 = in2[2];
    v[0] = p0.x; v[1] = p0.y; v[2] = p1.x; v[3] = p1.y; v[4] = p2.x; v[5] = p2.y;
    float m = v[0];
#pragma unroll
    for (int a = 1; a < NA; ++a) m = fmaxf(m, v[a]);
    float s = 0.0f;
#pragma unroll
    for (int a = 0; a < NA; ++a) { v[a] = expf(v[a] - m); s += v[a]; }
    float inv = 1.0f / s;
    float2* o2 = (float2*)(scores + (size_t)pos * NA);
    unsigned int* hb = hist + (size_t)b * SHBIN;
#pragma unroll
    for (int a = 0; a < NA; ++a) v[a] *= inv;
    o2[0] = make_float2(v[0], v[1]);
    o2[1] = make_float2(v[2], v[3]);
    o2[2] = make_float2(v[4], v[5]);
    // bins < BIN_LO can never be top-2000 (>=8192 scores/batch >= 1/6)
#pragma unroll
    for (int a = 0; a < NA; ++a) {
        unsigned int bin = __float_as_uint(v[a]) >> 16;
        if (bin >= BIN_LO) atomicAdd(&hb[bin - SH_BASE], 1u);
    }
}

// ------- K2: atomic-free gather; each block derives cut from raw hist --------
__global__ __launch_bounds__(256) void k_gather(
        const float* __restrict__ scores, const unsigned int* __restrict__ hist,
        u64* __restrict__ cand, unsigned int* __restrict__ counts) {
    const int blk = blockIdx.x;
    const int b = blk / SEGS, kb = blk - b * SEGS;
    const int tid = threadIdx.x;
    const int lane = tid & 63, w = tid >> 6;
    __shared__ unsigned int s_wsum[4];
    __shared__ unsigned int s_cut;
    __shared__ unsigned int s_wcnt[4];

    // ---- inline cut: thread t owns bins [base, base+1], t=0 at the top ----
    const unsigned int* hb = hist + (size_t)b * SHBIN;
    const int base = SHBIN - 2 * (tid + 1);
    unsigned int hlo = hb[base], hhi = hb[base + 1];
    unsigned int s = hlo + hhi;
    unsigned int inc = s;
#pragma unroll
    for (int d = 1; d < 64; d <<= 1) {
        unsigned int v = __shfl_up(inc, d);
        if (lane >= d) inc += v;
    }
    if (lane == 63) s_wsum[w] = inc;
    __syncthreads();
    unsigned int woff = 0;
#pragma unroll
    for (int i = 0; i < 4; ++i) if (i < w) woff += s_wsum[i];
    unsigned int excl = woff + inc - s;  // keys in bins above this pair
    if (excl < PRE_K && excl + s >= PRE_K) {
        unsigned int run = excl + hhi;   // after the higher bin of the pair
        s_cut = SH_BASE + (unsigned int)(run >= PRE_K ? base + 1 : base);
    }
    __syncthreads();
    const unsigned int cutr = s_cut;

    // ---- ballot-ranked private-segment gather (proven r3 structure) ----
    const int idx = kb * 256 + tid;                       // batch-local anchor
    const unsigned int bits = __float_as_uint(scores[(size_t)b * NANCH + idx]);
    const bool pass = (bits >> 16) >= cutr;
    const u64 m = __ballot(pass);
    if (lane == 0) s_wcnt[w] = (unsigned int)__popcll(m);
    __syncthreads();
    unsigned int pre = 0, tot = 0;
#pragma unroll
    for (int i = 0; i < 4; ++i) { unsigned int c = s_wcnt[i]; if (i < w) pre += c; tot += c; }
    if (pass) {
        unsigned int rank = pre + (unsigned int)__popcll(m & ((1ull << lane) - 1ull));
        cand[((size_t)b * SEGS + kb) * 256 + rank] =
            ((u64)bits << 32) | (unsigned int)(~idx);
    }
    if (tid == 0) counts[b * SEGS + kb] = tot;
}

// ---- K3: counting-sort rank + decode; sfx built in LDS from raw hist --------
__global__ __launch_bounds__(1024) void k_rankdec(
        const u64* __restrict__ cand, const unsigned int* __restrict__ counts,
        const unsigned int* __restrict__ hist,
        const float* __restrict__ deltas, const float* __restrict__ anchors,
        float4* __restrict__ pre_boxes, float* __restrict__ pre_scores) {
    const int b = blockIdx.x;
    const int tid = threadIdx.x;
    const int lane = tid & 63, wid = tid >> 6;
    __shared__ u64 grouped[CAND_CAP];         // 32KB
    __shared__ unsigned int cursor[CAND_CAP]; // 16KB
    __shared__ unsigned int sfx_lds[SHBIN];   // 2KB
    __shared__ unsigned int s_ws8[8];
    for (int i = tid; i < CAND_CAP; i += 1024) { grouped[i] = 0ull; cursor[i] = 0u; }

    // ---- inline sfx: first 512 threads, one bin each (tid 0 = top bin) ----
    unsigned int c = (tid < SHBIN) ? hist[(size_t)b * SHBIN + (SHBIN - 1 - tid)] : 0u;
    unsigned int inc = c;
#pragma unroll
    for (int d = 1; d < 64; d <<= 1) {
        unsigned int v = __shfl_up(inc, d);
        if (lane >= d) inc += v;
    }
    if (lane == 63 && wid < 8) s_ws8[wid] = inc;
    __syncthreads();   // covers zero-fill + s_ws8
    if (tid < SHBIN) {
        unsigned int woff = 0;
#pragma unroll
        for (int i = 0; i < 8; ++i) if (i < wid) woff += s_ws8[i];
        sfx_lds[SHBIN - 1 - tid] = woff + inc - c;   // keys strictly above bin
    }
    __syncthreads();

    // ---- placement: 192 threads walk their segment ----
    if (tid < SEGS) {
        unsigned int v = counts[b * SEGS + tid];
        const u64* seg = cand + ((size_t)b * SEGS + tid) * 256;
        for (unsigned int k = 0; k < v; ++k) {
            u64 key = seg[k];
            unsigned int bin = (unsigned int)(key >> 48) - SH_BASE;
            unsigned int g0 = sfx_lds[bin];            // group base < n
            unsigned int slot = g0 + atomicAdd(&cursor[g0], 1u);
            if (slot < CAND_CAP) grouped[slot] = key;
        }
    }
    __syncthreads();

    // ---- rank + decode (keys never 0: score>0 and ~idx!=0) ----
    for (int p = tid; p < CAND_CAP; p += 1024) {
        u64 key = grouped[p];
        if (key == 0ull) continue;
        unsigned int bin = (unsigned int)(key >> 48) - SH_BASE;
        unsigned int g0 = sfx_lds[bin];
        unsigned int cg = cursor[g0];
        unsigned int rank = g0;
        unsigned int qe = g0 + cg; if (qe > CAND_CAP) qe = CAND_CAP;
        for (unsigned int q = g0; q < qe; ++q) rank += (grouped[q] > key);
        if (rank < PRE_K) {
            int idx = (int)(~(unsigned int)key);
            float score = __uint_as_float((unsigned int)(key >> 32));
            const float* anc = anchors + (size_t)idx * 4;
            const float* del = deltas + ((size_t)b * NANCH + idx) * 4;
            float a0 = anc[0], a1 = anc[1], a2 = anc[2], a3 = anc[3];
            float ah = a2 - a0, aw = a3 - a1;
            float acy = a0 + 0.5f * ah, acx = a1 + 0.5f * aw;
            float d0 = del[0] * 0.1f, d1 = del[1] * 0.1f;
            float d2 = del[2] * 0.2f, d3 = del[3] * 0.2f;
            float bh = expf(d2) * ah, bw = expf(d3) * aw;
            float bcy = d0 * ah + acy, bcx = d1 * aw + acx;
            float y1 = bcy - 0.5f * bh, x1 = bcx - 0.5f * bw;
            pre_boxes[(size_t)b * PRE_K + rank] = make_float4(y1, x1, y1 + bh, x1 + bw);
            pre_scores[(size_t)b * PRE_K + rank] = score;
        }
    }
}

// ---------------- K4: suppression bit-matrix, rows < RMAX_EP*64 only ---------
__global__ __launch_bounds__(64) void k_iou(const float4* __restrict__ pre_boxes,
                                            u64* __restrict__ supp) {
    const int cb = blockIdx.x;   // col word 0..31
    const int rb = blockIdx.y;   // row block 0..RMAX_EP-1
    const int b  = blockIdx.z;
    const int lane = threadIdx.x;
    const int i = rb * 64 + lane;
    const int j0 = cb * 64;
    if (cb < rb) return;
    __shared__ float4 sbox[64];
    const float4* boxes = pre_boxes + (size_t)b * PRE_K;
    int j = j0 + lane;
    sbox[lane] = (j < PRE_K) ? boxes[j] : make_float4(0.f, 0.f, 0.f, 0.f);
    __syncthreads();
    if (i >= PRE_K) return;
    float4 bi = boxes[i];
    float area_i = (bi.z - bi.x) * (bi.w - bi.y);
    u64 bits = 0ull;
    const int tmax = (PRE_K - j0 < 64) ? (PRE_K - j0) : 64;
    for (int t = 0; t < tmax; ++t) {
        int jj = j0 + t;
        if (jj <= i) continue;
        float4 bj = sbox[t];
        float iy1 = fmaxf(bi.x, bj.x), ix1 = fmaxf(bi.y, bj.y);
        float iy2 = fminf(bi.z, bj.z), ix2 = fminf(bi.w, bj.w);
        float inter = fmaxf(iy2 - iy1, 0.0f) * fmaxf(ix2 - ix1, 0.0f);
        float area_j = (bj.z - bj.x) * (bj.w - bj.y);
        float uni = area_i + area_j - inter;
        float iou = inter / fmaxf(uni, 1e-8f);
        if (iou > 0.7f) bits |= (1ull << t);
    }
    supp[((size_t)b * PRE_K + i) * 32 + cb] = bits;
}

// ---------------- K5: serial greedy reduce + compact + outputs ----------------
__device__ __forceinline__ u64 readlane64(u64 x, int ln) {
    unsigned int lo = __builtin_amdgcn_readlane((unsigned int)x, ln);
    unsigned int hi = __builtin_amdgcn_readlane((unsigned int)(x >> 32), ln);
    return ((u64)hi << 32) | (u64)lo;
}

template <int ROWS>
__device__ __forceinline__ u64 proc_epoch(const u64* __restrict__ bufp, int wi,
                                          int p, int w, u64& r0, u64& r1) {
    const u64 wmask = (w >= wi) ? ~0ull : 0ull;  // unwritten words -> 0
    u64 acc = r0 | r1;
    u64 cur = ~(readlane64(acc, wi) | readlane64(acc, 32 + wi));
#pragma unroll
    for (int g = 0; g < ROWS / 16; ++g) {
        u64 ld[8];
#pragma unroll
        for (int k = 0; k < 8; ++k)
            ld[k] = bufp[(g * 16 + 2 * k + p) * 32 + w] & wmask;
        u64 t0 = (ld[0] | ld[1]) | (ld[2] | ld[3]);
        u64 t1 = (ld[4] | ld[5]) | (ld[6] | ld[7]);
        u64 tor = t0 | t1;
        u64 intra = readlane64(tor, wi) | readlane64(tor, 32 + wi);
        if (intra == 0ull) {
#pragma unroll
            for (int k = 0; k < 8; ++k) {
                int bitpos = g * 16 + 2 * k + p;
                u64 msk = ((cur >> bitpos) & 1ull) ? ~0ull : 0ull;
                if (k & 1) r1 |= ld[k] & msk; else r0 |= ld[k] & msk;
            }
        } else {
#pragma unroll
            for (int c = 0; c < 16; ++c) {
                const int pi = c & 1, k = c >> 1;
                if ((cur >> (g * 16 + c)) & 1ull) {
                    cur &= ~readlane64(ld[k], pi * 32 + wi);
                    u64 msk = (p == pi) ? ~0ull : 0ull;
                    if (k & 1) r1 |= ld[k] & msk; else r0 |= ld[k] & msk;
                }
            }
        }
    }
    return cur;
}

// inline fallback for epochs >= RMAX_EP (bit-identical IoU; rarely taken)
__device__ void fill_epoch(u64* __restrict__ dst, const float4* __restrict__ boxes,
                           int e, int l, int rows) {
    const int total = rows * 32;
    for (int idx = l; idx < total; idx += 64) {
        const int rl = idx >> 5, w = idx & 31;
        const int i = e * 64 + rl;
        const int j0 = w * 64;
        u64 bits = 0ull;
        if (i < PRE_K && j0 + 63 > i) {
            float4 bi = boxes[i];
            float area_i = (bi.z - bi.x) * (bi.w - bi.y);
            const int tmax = (PRE_K - j0 < 64) ? (PRE_K - j0) : 64;
            for (int t = 0; t < tmax; ++t) {
                int jj = j0 + t;
                if (jj <= i) continue;
                float4 bj = boxes[jj];
                float iy1 = fmaxf(bi.x, bj.x), ix1 = fmaxf(bi.y, bj.y);
                float iy2 = fminf(bi.z, bj.z), ix2 = fminf(bi.w, bj.w);
                float inter = fmaxf(iy2 - iy1, 0.0f) * fmaxf(ix2 - ix1, 0.0f);
                float area_j = (bj.z - bj.x) * (bj.w - bj.y);
                float uni = area_i + area_j - inter;
                float iou = inter / fmaxf(uni, 1e-8f);
                if (iou > 0.7f) bits |= (1ull << t);
            }
        }
        dst[idx] = bits;
    }
}

__global__ __launch_bounds__(64) void k_final(const u64* __restrict__ supp,
                        const float4* __restrict__ pre_boxes,
                        const float* __restrict__ pre_scores,
                        float* __restrict__ out) {
    const int b = blockIdx.x;
    const int l = threadIdx.x;
    const int p = l >> 5, w = l & 31;
    float* ob = out + (size_t)b * POST_K * 4;
    float* os = out + (size_t)BATCH * POST_K * 4 + (size_t)b * POST_K;
    for (int t = l; t < POST_K * 4; t += 64) ob[t] = 0.0f;
    for (int t = l; t < POST_K; t += 64) os[t] = 0.0f;
    asm volatile("s_waitcnt vmcnt(0)" ::: "memory");

    __shared__ u64 sbuf[5][2048];   // 5 x 16KB: depth-4 prefetch ring
    const char* Sb = (const char*)(supp + (size_t)b * PRE_K * 32);
    const float4* boxes = pre_boxes + (size_t)b * PRE_K;

#define ISSUE_EPOCH(ep)                                                       \
    do {                                                                      \
        const char* gsrc_ = Sb + (size_t)(ep) * 16384 + (size_t)l * 16;       \
        char* ldst_ = (char*)&sbuf[(ep) % 5][0];                              \
        _Pragma("unroll")                                                     \
        for (int k_ = 0; k_ < 16; ++k_)                                       \
            __builtin_amdgcn_global_load_lds(                                 \
                (const __attribute__((address_space(1))) void*)(gsrc_ + k_ * 1024), \
                (__attribute__((address_space(3))) void*)(ldst_ + k_ * 1024), \
                16, 0, 0);                                                    \
    } while (0)

    u64 r0 = 0ull, r1 = 0ull;
    int kept = 0;
    bool done = false;
    ISSUE_EPOCH(0);
    ISSUE_EPOCH(1);
    ISSUE_EPOCH(2);
    ISSUE_EPOCH(3);
    for (int e = 0; e < RMAX_EP; ++e) {
        // wait until epoch e landed (compile-time vmcnt ladder)
        if (e <= RMAX_EP - 4)      asm volatile("s_waitcnt vmcnt(48)" ::: "memory");
        else if (e == RMAX_EP - 3) asm volatile("s_waitcnt vmcnt(32)" ::: "memory");
        else if (e == RMAX_EP - 2) asm volatile("s_waitcnt vmcnt(16)" ::: "memory");
        else                       asm volatile("s_waitcnt vmcnt(0)"  ::: "memory");
        __builtin_amdgcn_sched_barrier(0);
        if (e + 4 < RMAX_EP) ISSUE_EPOCH(e + 4);   // ring slot (e+4)%5 != e%5
        u64 curf = proc_epoch<64>(&sbuf[e % 5][0], e, p, w, r0, r1);
        kept += __builtin_popcountll(curf);   // wave-uniform
        if (kept >= POST_K) { done = true; break; }
    }
    asm volatile("s_waitcnt vmcnt(0)" ::: "memory");  // drain leftover prefetch
    if (!done) {
        for (int e = RMAX_EP; e < 32; ++e) {       // inline-IoU fallback epochs
            fill_epoch(&sbuf[0][0], boxes, e, l, (e == 31) ? 16 : 64);
            __syncthreads();
            u64 curf;
            if (e < 31) curf = proc_epoch<64>(&sbuf[0][0], e, p, w, r0, r1);
            else        curf = proc_epoch<16>(&sbuf[0][0], e, p, w, r0, r1) & 0xFFFFull;
            kept += __builtin_popcountll(curf);
            if (kept >= POST_K) break;
            __syncthreads();
        }
    }
#undef ISSUE_EPOCH

    u64 full = r0 | r1;
    u64 oth = __shfl(full, w + 32);
    u64 kw = ~(full | oth);
    if (w == 31) kw &= 0xFFFFull;
    int cnt = (l < 32) ? __builtin_popcountll(kw) : 0;
    int cum = cnt;
#pragma unroll
    for (int d = 1; d < 64; d <<= 1) {
        int v = __shfl_up(cum, d);
        if (l >= d) cum += v;
    }
    int r = cum - cnt;
    __syncthreads();
    if (l < 32) {
        u64 m = kw;
        while (m != 0ull && r < POST_K) {
            int t = __builtin_ctzll(m);
            m &= m - 1ull;
            int i = w * 64 + t;
            float4 bx = pre_boxes[(size_t)b * PRE_K + i];
            ob[r * 4 + 0] = fminf(fmaxf(bx.x, 0.0f), 1.0f);
            ob[r * 4 + 1] = fminf(fmaxf(bx.y, 0.0f), 1.0f);
            ob[r * 4 + 2] = fminf(fmaxf(bx.z, 0.0f), 1.0f);
            ob[r * 4 + 3] = fminf(fmaxf(bx.w, 0.0f), 1.0f);
            os[r] = pre_scores[(size_t)b * PRE_K + i];
            ++r;
        }
    }
}

extern "C" void kernel_launch(void* const* d_in, const int* in_sizes, int n_in,
                              void* d_out, int out_size, void* d_ws, size_t ws_size,
                              hipStream_t stream) {
    const float* deltas  = (const float*)d_in[0];
    const float* labels  = (const float*)d_in[1];
    const float* anchors = (const float*)d_in[2];
    float* out = (float*)d_out;

    char* ws = (char*)d_ws;
    float* scores          = (float*)(ws + WS_SC);
    unsigned int* hist     = (unsigned int*)(ws + WS_HIST);   // raw counts
    u64* cd                = (u64*)(ws + WS_CAND);
    unsigned int* cntp     = (unsigned int*)(ws + WS_CNT);
    float4* pre_boxes      = (float4*)(ws + WS_PB);
    float* pre_scores      = (float*)(ws + WS_PS);
    u64* sp                = (u64*)(ws + WS_SUPP);

    k_zero<<<1, 1024, 0, stream>>>((uint4*)hist);
    k_softhist<<<(BATCH * FHh * FWw + 255) / 256, 256, 0, stream>>>(labels, scores, hist);
    k_gather<<<BATCH * SEGS, 256, 0, stream>>>(scores, hist, cd, cntp);
    k_rankdec<<<BATCH, 1024, 0, stream>>>(cd, cntp, hist, deltas, anchors,
                                          pre_boxes, pre_scores);
    k_iou<<<dim3(32, RMAX_EP, BATCH), 64, 0, stream>>>(pre_boxes, sp);
    k_final<<<BATCH, 64, 0, stream>>>(sp, pre_boxes, pre_scores, out);
}

// Round 17
// 86.791 us; speedup vs baseline: 1.0039x; 1.0039x over previous
//
#include <hip/hip_runtime.h>
#include <cstdint>
#include <cstddef>

#define BATCH 8
#define FHh   32
#define FWw   256
#define NA    6
#define NANCH (FHh * FWw * NA)   // 49152
#define PRE_K 2000
#define POST_K 300
#define SEGS  192                // blocks per batch in k_gather
#define CAND_CAP 4096
#define BIN_LO 0x3E2Au           // bin(1/6): 2000th key's bin >= this
#define SH_BASE 0x3E00u          // small-hist base; covers [0x3E00, 0x4000)
#define SHBIN 512                // scores <= 1.0 -> bin <= 0x3F80 < 0x4000
#define RMAX_EP 20               // k_iou precomputes epochs [0,20); rest inline
#define NBUF 8                   // k_final LDS ring (8 x 16KB = 128KB)

typedef unsigned long long u64;

// -------- workspace layout (bytes); d_ws is 256 MiB — all regions disjoint ---
#define WS_SC   0                 // scores   1,572,864
#define WS_HIST 1572864           // raw 512-bin hist, 8*512*4 = 16,384
#define WS_CAND 4194304           // 8*192*256*8 = 3,145,728
#define WS_CNT  7340032           // 8*192*4 = 6,144
#define WS_PB   7602176           // pre_boxes 256,000
#define WS_PS   7858176           // pre_scores 64,000
#define WS_SUPP 8388608           // supp (rows < RMAX_EP*64, upper-tri written)

// ---------------- K0: zero the 16KB histogram (one block) --------------------
__global__ __launch_bounds__(1024) void k_zero(uint4* __restrict__ hist4) {
    hist4[threadIdx.x] = make_uint4(0u, 0u, 0u, 0u);   // 1024 x 16B = 16KB
}

// ---------------- K1: fused softmax + pruned 512-bin histogram ---------------
__global__ void k_softhist(const float* __restrict__ labels, float* __restrict__ scores,
                           unsigned int* __restrict__ hist) {
    int pos = blockIdx.x * blockDim.x + threadIdx.x;  // over BATCH*FH*FW
    if (pos >= BATCH * FHh * FWw) return;
    int b = pos / (FHh * FWw);
    const float2* in2 = (const float2*)(labels + (size_t)pos * NA);
    float v[NA];
    float2 p0 = in2[0], p1 = in2[1], p2 = in2[2];
    v[0] = p0.x; v[1] = p0.y; v[2] = p1.x; v[3] = p1.y; v[4] = p2.x; v[5] = p2.y;
    float m = v[0];
#pragma unroll
    for (int a = 1; a < NA; ++a) m = fmaxf(m, v[a]);
    float s = 0.0f;
#pragma unroll
    for (int a = 0; a < NA; ++a) { v[a] = expf(v[a] - m); s += v[a]; }
    float inv = 1.0f / s;
    float2* o2 = (float2*)(scores + (size_t)pos * NA);
    unsigned int* hb = hist + (size_t)b * SHBIN;
#pragma unroll
    for (int a = 0; a < NA; ++a) v[a] *= inv;
    o2[0] = make_float2(v[0], v[1]);
    o2[1] = make_float2(v[2], v[3]);
    o2[2] = make_float2(v[4], v[5]);
    // bins < BIN_LO can never be top-2000 (>=8192 scores/batch >= 1/6)
#pragma unroll
    for (int a = 0; a < NA; ++a) {
        unsigned int bin = __float_as_uint(v[a]) >> 16;
        if (bin >= BIN_LO) atomicAdd(&hb[bin - SH_BASE], 1u);
    }
}

// ------- K2: atomic-free gather; each block derives cut from raw hist --------
__global__ __launch_bounds__(256) void k_gather(
        const float* __restrict__ scores, const unsigned int* __restrict__ hist,
        u64* __restrict__ cand, unsigned int* __restrict__ counts) {
    const int blk = blockIdx.x;
    const int b = blk / SEGS, kb = blk - b * SEGS;
    const int tid = threadIdx.x;
    const int lane = tid & 63, w = tid >> 6;
    __shared__ unsigned int s_wsum[4];
    __shared__ unsigned int s_cut;
    __shared__ unsigned int s_wcnt[4];

    // ---- inline cut: thread t owns bins [base, base+1], t=0 at the top ----
    const unsigned int* hb = hist + (size_t)b * SHBIN;
    const int base = SHBIN - 2 * (tid + 1);
    unsigned int hlo = hb[base], hhi = hb[base + 1];
    unsigned int s = hlo + hhi;
    unsigned int inc = s;
#pragma unroll
    for (int d = 1; d < 64; d <<= 1) {
        unsigned int v = __shfl_up(inc, d);
        if (lane >= d) inc += v;
    }
    if (lane == 63) s_wsum[w] = inc;
    __syncthreads();
    unsigned int woff = 0;
#pragma unroll
    for (int i = 0; i < 4; ++i) if (i < w) woff += s_wsum[i];
    unsigned int excl = woff + inc - s;  // keys in bins above this pair
    if (excl < PRE_K && excl + s >= PRE_K) {
        unsigned int run = excl + hhi;   // after the higher bin of the pair
        s_cut = SH_BASE + (unsigned int)(run >= PRE_K ? base + 1 : base);
    }
    __syncthreads();
    const unsigned int cutr = s_cut;

    // ---- ballot-ranked private-segment gather (proven r3 structure) ----
    const int idx = kb * 256 + tid;                       // batch-local anchor
    const unsigned int bits = __float_as_uint(scores[(size_t)b * NANCH + idx]);
    const bool pass = (bits >> 16) >= cutr;
    const u64 m = __ballot(pass);
    if (lane == 0) s_wcnt[w] = (unsigned int)__popcll(m);
    __syncthreads();
    unsigned int pre = 0, tot = 0;
#pragma unroll
    for (int i = 0; i < 4; ++i) { unsigned int c = s_wcnt[i]; if (i < w) pre += c; tot += c; }
    if (pass) {
        unsigned int rank = pre + (unsigned int)__popcll(m & ((1ull << lane) - 1ull));
        cand[((size_t)b * SEGS + kb) * 256 + rank] =
            ((u64)bits << 32) | (unsigned int)(~idx);
    }
    if (tid == 0) counts[b * SEGS + kb] = tot;
}

// ---- K3: counting-sort rank + decode; sfx built in LDS from raw hist --------
__global__ __launch_bounds__(1024) void k_rankdec(
        const u64* __restrict__ cand, const unsigned int* __restrict__ counts,
        const unsigned int* __restrict__ hist,
        const float* __restrict__ deltas, const float* __restrict__ anchors,
        float4* __restrict__ pre_boxes, float* __restrict__ pre_scores) {
    const int b = blockIdx.x;
    const int tid = threadIdx.x;
    const int lane = tid & 63, wid = tid >> 6;
    __shared__ u64 grouped[CAND_CAP];         // 32KB
    __shared__ unsigned int cursor[CAND_CAP]; // 16KB
    __shared__ unsigned int sfx_lds[SHBIN];   // 2KB
    __shared__ unsigned int s_ws8[8];
    for (int i = tid; i < CAND_CAP; i += 1024) { grouped[i] = 0ull; cursor[i] = 0u; }

    // ---- inline sfx: first 512 threads, one bin each (tid 0 = top bin) ----
    unsigned int c = (tid < SHBIN) ? hist[(size_t)b * SHBIN + (SHBIN - 1 - tid)] : 0u;
    unsigned int inc = c;
#pragma unroll
    for (int d = 1; d < 64; d <<= 1) {
        unsigned int v = __shfl_up(inc, d);
        if (lane >= d) inc += v;
    }
    if (lane == 63 && wid < 8) s_ws8[wid] = inc;
    __syncthreads();   // covers zero-fill + s_ws8
    if (tid < SHBIN) {
        unsigned int woff = 0;
#pragma unroll
        for (int i = 0; i < 8; ++i) if (i < wid) woff += s_ws8[i];
        sfx_lds[SHBIN - 1 - tid] = woff + inc - c;   // keys strictly above bin
    }
    __syncthreads();

    // ---- placement: 192 threads walk their segment ----
    if (tid < SEGS) {
        unsigned int v = counts[b * SEGS + tid];
        const u64* seg = cand + ((size_t)b * SEGS + tid) * 256;
        for (unsigned int k = 0; k < v; ++k) {
            u64 key = seg[k];
            unsigned int bin = (unsigned int)(key >> 48) - SH_BASE;
            unsigned int g0 = sfx_lds[bin];            // group base < n
            unsigned int slot = g0 + atomicAdd(&cursor[g0], 1u);
            if (slot < CAND_CAP) grouped[slot] = key;
        }
    }
    __syncthreads();

    // ---- rank + decode (keys never 0: score>0 and ~idx!=0) ----
    for (int p = tid; p < CAND_CAP; p += 1024) {
        u64 key = grouped[p];
        if (key == 0ull) continue;
        unsigned int bin = (unsigned int)(key >> 48) - SH_BASE;
        unsigned int g0 = sfx_lds[bin];
        unsigned int cg = cursor[g0];
        unsigned int rank = g0;
        unsigned int qe = g0 + cg; if (qe > CAND_CAP) qe = CAND_CAP;
        for (unsigned int q = g0; q < qe; ++q) rank += (grouped[q] > key);
        if (rank < PRE_K) {
            int idx = (int)(~(unsigned int)key);
            float score = __uint_as_float((unsigned int)(key >> 32));
            const float* anc = anchors + (size_t)idx * 4;
            const float* del = deltas + ((size_t)b * NANCH + idx) * 4;
            float a0 = anc[0], a1 = anc[1], a2 = anc[2], a3 = anc[3];
            float ah = a2 - a0, aw = a3 - a1;
            float acy = a0 + 0.5f * ah, acx = a1 + 0.5f * aw;
            float d0 = del[0] * 0.1f, d1 = del[1] * 0.1f;
            float d2 = del[2] * 0.2f, d3 = del[3] * 0.2f;
            float bh = expf(d2) * ah, bw = expf(d3) * aw;
            float bcy = d0 * ah + acy, bcx = d1 * aw + acx;
            float y1 = bcy - 0.5f * bh, x1 = bcx - 0.5f * bw;
            pre_boxes[(size_t)b * PRE_K + rank] = make_float4(y1, x1, y1 + bh, x1 + bw);
            pre_scores[(size_t)b * PRE_K + rank] = score;
        }
    }
}

// ---------------- K4: suppression bit-matrix, rows < RMAX_EP*64 only ---------
__global__ __launch_bounds__(64) void k_iou(const float4* __restrict__ pre_boxes,
                                            u64* __restrict__ supp) {
    const int cb = blockIdx.x;   // col word 0..31
    const int rb = blockIdx.y;   // row block 0..RMAX_EP-1
    const int b  = blockIdx.z;
    const int lane = threadIdx.x;
    const int i = rb * 64 + lane;
    const int j0 = cb * 64;
    if (cb < rb) return;
    __shared__ float4 sbox[64];
    const float4* boxes = pre_boxes + (size_t)b * PRE_K;
    int j = j0 + lane;
    sbox[lane] = (j < PRE_K) ? boxes[j] : make_float4(0.f, 0.f, 0.f, 0.f);
    __syncthreads();
    if (i >= PRE_K) return;
    float4 bi = boxes[i];
    float area_i = (bi.z - bi.x) * (bi.w - bi.y);
    u64 bits = 0ull;
    const int tmax = (PRE_K - j0 < 64) ? (PRE_K - j0) : 64;
    for (int t = 0; t < tmax; ++t) {
        int jj = j0 + t;
        if (jj <= i) continue;
        float4 bj = sbox[t];
        float iy1 = fmaxf(bi.x, bj.x), ix1 = fmaxf(bi.y, bj.y);
        float iy2 = fminf(bi.z, bj.z), ix2 = fminf(bi.w, bj.w);
        float inter = fmaxf(iy2 - iy1, 0.0f) * fmaxf(ix2 - ix1, 0.0f);
        float area_j = (bj.z - bj.x) * (bj.w - bj.y);
        float uni = area_i + area_j - inter;
        float iou = inter / fmaxf(uni, 1e-8f);
        if (iou > 0.7f) bits |= (1ull << t);
    }
    supp[((size_t)b * PRE_K + i) * 32 + cb] = bits;
}

// ---------------- K5: greedy reduce, producer/consumer multi-wave staging ----
__device__ __forceinline__ u64 readlane64(u64 x, int ln) {
    unsigned int lo = __builtin_amdgcn_readlane((unsigned int)x, ln);
    unsigned int hi = __builtin_amdgcn_readlane((unsigned int)(x >> 32), ln);
    return ((u64)hi << 32) | (u64)lo;
}

template <int ROWS>
__device__ __forceinline__ u64 proc_epoch(const u64* __restrict__ bufp, int wi,
                                          int p, int w, u64& r0, u64& r1) {
    const u64 wmask = (w >= wi) ? ~0ull : 0ull;  // unwritten words -> 0
    u64 acc = r0 | r1;
    u64 cur = ~(readlane64(acc, wi) | readlane64(acc, 32 + wi));
#pragma unroll
    for (int g = 0; g < ROWS / 16; ++g) {
        u64 ld[8];
#pragma unroll
        for (int k = 0; k < 8; ++k)
            ld[k] = bufp[(g * 16 + 2 * k + p) * 32 + w] & wmask;
        u64 t0 = (ld[0] | ld[1]) | (ld[2] | ld[3]);
        u64 t1 = (ld[4] | ld[5]) | (ld[6] | ld[7]);
        u64 tor = t0 | t1;
        u64 intra = readlane64(tor, wi) | readlane64(tor, 32 + wi);
        if (intra == 0ull) {
#pragma unroll
            for (int k = 0; k < 8; ++k) {
                int bitpos = g * 16 + 2 * k + p;
                u64 msk = ((cur >> bitpos) & 1ull) ? ~0ull : 0ull;
                if (k & 1) r1 |= ld[k] & msk; else r0 |= ld[k] & msk;
            }
        } else {
#pragma unroll
            for (int c = 0; c < 16; ++c) {
                const int pi = c & 1, k = c >> 1;
                if ((cur >> (g * 16 + c)) & 1ull) {
                    cur &= ~readlane64(ld[k], pi * 32 + wi);
                    u64 msk = (p == pi) ? ~0ull : 0ull;
                    if (k & 1) r1 |= ld[k] & msk; else r0 |= ld[k] & msk;
                }
            }
        }
    }
    return cur;
}

// inline fallback for epochs >= RMAX_EP (bit-identical IoU; rarely taken)
__device__ void fill_epoch(u64* __restrict__ dst, const float4* __restrict__ boxes,
                           int e, int l, int nthreads, int rows) {
    const int total = rows * 32;
    for (int idx = l; idx < total; idx += nthreads) {
        const int rl = idx >> 5, w = idx & 31;
        const int i = e * 64 + rl;
        const int j0 = w * 64;
        u64 bits = 0ull;
        if (i < PRE_K && j0 + 63 > i) {
            float4 bi = boxes[i];
            float area_i = (bi.z - bi.x) * (bi.w - bi.y);
            const int tmax = (PRE_K - j0 < 64) ? (PRE_K - j0) : 64;
            for (int t = 0; t < tmax; ++t) {
                int jj = j0 + t;
                if (jj <= i) continue;
                float4 bj = boxes[jj];
                float iy1 = fmaxf(bi.x, bj.x), ix1 = fmaxf(bi.y, bj.y);
                float iy2 = fminf(bi.z, bj.z), ix2 = fminf(bi.w, bj.w);
                float inter = fmaxf(iy2 - iy1, 0.0f) * fmaxf(ix2 - ix1, 0.0f);
                float area_j = (bj.z - bj.x) * (bj.w - bj.y);
                float uni = area_i + area_j - inter;
                float iou = inter / fmaxf(uni, 1e-8f);
                if (iou > 0.7f) bits |= (1ull << t);
            }
        }
        dst[idx] = bits;
    }
}

#define LDS_LD(p)  __hip_atomic_load((p), __ATOMIC_ACQUIRE, __HIP_MEMORY_SCOPE_WORKGROUP)
#define LDS_ST(p, v) __hip_atomic_store((p), (v), __ATOMIC_RELEASE, __HIP_MEMORY_SCOPE_WORKGROUP)

__global__ __launch_bounds__(512) void k_final(const u64* __restrict__ supp,
                        const float4* __restrict__ pre_boxes,
                        const float* __restrict__ pre_scores,
                        float* __restrict__ out) {
    const int b = blockIdx.x;
    const int l = threadIdx.x;
    const int wv = l >> 6;        // wave 0 = consumer; waves 1..7 = producers
    const int lw = l & 63;
    const int p = lw >> 5, w = lw & 31;
    float* ob = out + (size_t)b * POST_K * 4;
    float* os = out + (size_t)BATCH * POST_K * 4 + (size_t)b * POST_K;
    for (int t = l; t < POST_K * 4; t += 512) ob[t] = 0.0f;
    for (int t = l; t < POST_K; t += 512) os[t] = 0.0f;

    __shared__ u64 sbuf[NBUF][2048];     // 128KB epoch ring
    __shared__ int s_ready[RMAX_EP];
    __shared__ int s_consumed;
    __shared__ int s_abort;
    __shared__ int s_done;
    __shared__ int s_kept;
    if (l < RMAX_EP) s_ready[l] = 0;
    if (l == 0) { s_consumed = 0; s_abort = 0; s_done = 0; s_kept = 0; }
    __syncthreads();   // also drains the zero-fill stores (vmcnt0 before barrier)

    const char* Sb = (const char*)(supp + (size_t)b * PRE_K * 32);
    const float4* boxes = pre_boxes + (size_t)b * PRE_K;

    u64 r0 = 0ull, r1 = 0ull;
    int kept = 0;

    if (wv == 0) {
        // ---- consumer: serial greedy walk over staged epochs ----
        for (int e = 0; e < RMAX_EP; ++e) {
            while (LDS_LD(&s_ready[e]) == 0) __builtin_amdgcn_s_sleep(2);
            __builtin_amdgcn_sched_barrier(0);
            u64 curf = proc_epoch<64>(&sbuf[e % NBUF][0], e, p, w, r0, r1);
            kept += __builtin_popcountll(curf);   // wave-uniform
            LDS_ST(&s_consumed, e + 1);
            if (kept >= POST_K) break;            // exact early exit
        }
        if (lw == 0) {
            s_kept = kept;
            if (kept >= POST_K) s_done = 1;
            LDS_ST(&s_abort, 1);                  // release producers
        }
    } else {
        // ---- producers: stage every-7th epoch into the ring ----
        for (int e = wv - 1; e < RMAX_EP; e += 7) {
            bool bail = false;
            while (LDS_LD(&s_consumed) < e - (NBUF - 1)) {   // slot e%NBUF free?
                if (LDS_LD(&s_abort)) { bail = true; break; }
                __builtin_amdgcn_s_sleep(2);
            }
            if (bail || LDS_LD(&s_abort)) break;
            const char* gsrc = Sb + (size_t)e * 16384 + (size_t)lw * 16;
            char* ldst = (char*)&sbuf[e % NBUF][0];
#pragma unroll
            for (int k = 0; k < 16; ++k)
                __builtin_amdgcn_global_load_lds(
                    (const __attribute__((address_space(1))) void*)(gsrc + k * 1024),
                    (__attribute__((address_space(3))) void*)(ldst + lw * 16 + k * 1024),
                    16, 0, 0);
            asm volatile("s_waitcnt vmcnt(0)" ::: "memory");
            if (lw == 0) LDS_ST(&s_ready[e], 1);
        }
    }
    __syncthreads();
    kept = s_kept;   // broadcast (consumer's r0/r1 stay in wave 0 regs)

    // ---- fallback epochs >= RMAX_EP (uniform barriers; rarely taken) ----
    for (int e = RMAX_EP; e < 32; ++e) {
        if (s_done) break;                        // uniform: read post-barrier
        fill_epoch(&sbuf[0][0], boxes, e, l, 512, (e == 31) ? 16 : 64);
        __syncthreads();
        if (wv == 0) {
            u64 curf;
            if (e < 31) curf = proc_epoch<64>(&sbuf[0][0], e, p, w, r0, r1);
            else        curf = proc_epoch<16>(&sbuf[0][0], e, p, w, r0, r1) & 0xFFFFull;
            kept += __builtin_popcountll(curf);
            if (lw == 0 && kept >= POST_K) s_done = 1;
        }
        __syncthreads();
    }

    // ---- compact kept rows (wave 0 only; r0/r1 live there) ----
    if (wv == 0) {
        u64 full = r0 | r1;
        u64 oth = __shfl(full, w + 32);
        u64 kw = ~(full | oth);
        if (w == 31) kw &= 0xFFFFull;
        int cnt = (lw < 32) ? __builtin_popcountll(kw) : 0;
        int cum = cnt;
#pragma unroll
        for (int d = 1; d < 64; d <<= 1) {
            int v = __shfl_up(cum, d);
            if (lw >= d) cum += v;
        }
        int r = cum - cnt;
        if (lw < 32) {
            u64 m = kw;
            while (m != 0ull && r < POST_K) {
                int t = __builtin_ctzll(m);
                m &= m - 1ull;
                int i = w * 64 + t;
                float4 bx = pre_boxes[(size_t)b * PRE_K + i];
                ob[r * 4 + 0] = fminf(fmaxf(bx.x, 0.0f), 1.0f);
                ob[r * 4 + 1] = fminf(fmaxf(bx.y, 0.0f), 1.0f);
                ob[r * 4 + 2] = fminf(fmaxf(bx.z, 0.0f), 1.0f);
                ob[r * 4 + 3] = fminf(fmaxf(bx.w, 0.0f), 1.0f);
                os[r] = pre_scores[(size_t)b * PRE_K + i];
                ++r;
            }
        }
    }
}

extern "C" void kernel_launch(void* const* d_in, const int* in_sizes, int n_in,
                              void* d_out, int out_size, void* d_ws, size_t ws_size,
                              hipStream_t stream) {
    const float* deltas  = (const float*)d_in[0];
    const float* labels  = (const float*)d_in[1];
    const float* anchors = (const float*)d_in[2];
    float* out = (float*)d_out;

    char* ws = (char*)d_ws;
    float* scores          = (float*)(ws + WS_SC);
    unsigned int* hist     = (unsigned int*)(ws + WS_HIST);   // raw counts
    u64* cd                = (u64*)(ws + WS_CAND);
    unsigned int* cntp     = (unsigned int*)(ws + WS_CNT);
    float4* pre_boxes      = (float4*)(ws + WS_PB);
    float* pre_scores      = (float*)(ws + WS_PS);
    u64* sp                = (u64*)(ws + WS_SUPP);

    k_zero<<<1, 1024, 0, stream>>>((uint4*)hist);
    k_softhist<<<(BATCH * FHh * FWw + 255) / 256, 256, 0, stream>>>(labels, scores, hist);
    k_gather<<<BATCH * SEGS, 256, 0, stream>>>(scores, hist, cd, cntp);
    k_rankdec<<<BATCH, 1024, 0, stream>>>(cd, cntp, hist, deltas, anchors,
                                          pre_boxes, pre_scores);
    k_iou<<<dim3(32, RMAX_EP, BATCH), 64, 0, stream>>>(pre_boxes, sp);
    k_final<<<BATCH, 512, 0, stream>>>(sp, pre_boxes, pre_scores, out);
}

// Round 18
// 72.553 us; speedup vs baseline: 1.2009x; 1.1962x over previous
//
#include <hip/hip_runtime.h>
#include <cstdint>
#include <cstddef>

#define BATCH 8
#define FHh   32
#define FWw   256
#define NA    6
#define NANCH (FHh * FWw * NA)   // 49152
#define PRE_K 2000
#define POST_K 300
#define SEGS  192                // blocks per batch in k_gather
#define CAND_CAP 4096
#define BIN_LO 0x3E2Au           // bin(1/6): 2000th key's bin >= this
#define SH_BASE 0x3E00u          // small-hist base; covers [0x3E00, 0x4000)
#define SHBIN 512                // scores <= 1.0 -> bin <= 0x3F80 < 0x4000
#define RMAX_EP 20               // k_iou precomputes epochs [0,20); rest inline
#define NBUF 8                   // k_final LDS ring (8 x 16KB = 128KB)

typedef unsigned long long u64;

// -------- workspace layout (bytes); d_ws is 256 MiB — all regions disjoint ---
#define WS_SC   0                 // scores   1,572,864
#define WS_HIST 1572864           // raw 512-bin hist, 8*512*4 = 16,384
#define WS_CAND 4194304           // 8*192*256*8 = 3,145,728
#define WS_CNT  7340032           // 8*192*4 = 6,144
#define WS_PB   7602176           // pre_boxes 256,000
#define WS_PS   7858176           // pre_scores 64,000
#define WS_SUPP 8388608           // supp (rows < RMAX_EP*64, upper-tri written)

// ---------------- K0: zero the 16KB histogram (one block) --------------------
__global__ __launch_bounds__(1024) void k_zero(uint4* __restrict__ hist4) {
    hist4[threadIdx.x] = make_uint4(0u, 0u, 0u, 0u);   // 1024 x 16B = 16KB
}

// ------ K1: fused softmax + LDS-aggregated 512-bin histogram -----------------
// r17 lesson: 235K device-scope atomics on ~340 hot L2 words serialize
// chip-wide. Aggregate per-block in LDS (parallel across CUs), flush once.
__global__ __launch_bounds__(256) void k_softhist(
        const float* __restrict__ labels, float* __restrict__ scores,
        unsigned int* __restrict__ hist) {
    const int blk = blockIdx.x;           // 256 blocks; 32 per batch
    const int b = blk >> 5;               // 8192 positions per batch / 256
    const int tid = threadIdx.x;
    __shared__ unsigned int lh[SHBIN];
    lh[tid] = 0u; lh[tid + 256] = 0u;
    __syncthreads();

    const int pos = blk * 256 + tid;      // global position in [0, 65536)
    const float2* in2 = (const float2*)(labels + (size_t)pos * NA);
    float v[NA];
    float2 p0 = in2[0], p1 = in2[1], p2 = in2[2];
    v[0] = p0.x; v[1] = p0.y; v[2] = p1.x; v[3] = p1.y; v[4] = p2.x; v[5] = p2.y;
    float m = v[0];
#pragma unroll
    for (int a = 1; a < NA; ++a) m = fmaxf(m, v[a]);
    float s = 0.0f;
#pragma unroll
    for (int a = 0; a < NA; ++a) { v[a] = expf(v[a] - m); s += v[a]; }
    float inv = 1.0f / s;
    float2* o2 = (float2*)(scores + (size_t)pos * NA);
#pragma unroll
    for (int a = 0; a < NA; ++a) v[a] *= inv;
    o2[0] = make_float2(v[0], v[1]);
    o2[1] = make_float2(v[2], v[3]);
    o2[2] = make_float2(v[4], v[5]);
    // bins < BIN_LO can never be top-2000 (>=8192 scores/batch >= 1/6)
#pragma unroll
    for (int a = 0; a < NA; ++a) {
        unsigned int bin = __float_as_uint(v[a]) >> 16;
        if (bin >= BIN_LO) atomicAdd(&lh[bin - SH_BASE], 1u);
    }
    __syncthreads();
    unsigned int* hb = hist + (size_t)b * SHBIN;
    unsigned int c0 = lh[tid];
    unsigned int c1 = lh[tid + 256];
    if (c0) atomicAdd(&hb[tid], c0);
    if (c1) atomicAdd(&hb[tid + 256], c1);
}

// ------- K2: atomic-free gather; each block derives cut from raw hist --------
__global__ __launch_bounds__(256) void k_gather(
        const float* __restrict__ scores, const unsigned int* __restrict__ hist,
        u64* __restrict__ cand, unsigned int* __restrict__ counts) {
    const int blk = blockIdx.x;
    const int b = blk / SEGS, kb = blk - b * SEGS;
    const int tid = threadIdx.x;
    const int lane = tid & 63, w = tid >> 6;
    __shared__ unsigned int s_wsum[4];
    __shared__ unsigned int s_cut;
    __shared__ unsigned int s_wcnt[4];

    // ---- inline cut: thread t owns bins [base, base+1], t=0 at the top ----
    const unsigned int* hb = hist + (size_t)b * SHBIN;
    const int base = SHBIN - 2 * (tid + 1);
    unsigned int hlo = hb[base], hhi = hb[base + 1];
    unsigned int s = hlo + hhi;
    unsigned int inc = s;
#pragma unroll
    for (int d = 1; d < 64; d <<= 1) {
        unsigned int v = __shfl_up(inc, d);
        if (lane >= d) inc += v;
    }
    if (lane == 63) s_wsum[w] = inc;
    __syncthreads();
    unsigned int woff = 0;
#pragma unroll
    for (int i = 0; i < 4; ++i) if (i < w) woff += s_wsum[i];
    unsigned int excl = woff + inc - s;  // keys in bins above this pair
    if (excl < PRE_K && excl + s >= PRE_K) {
        unsigned int run = excl + hhi;   // after the higher bin of the pair
        s_cut = SH_BASE + (unsigned int)(run >= PRE_K ? base + 1 : base);
    }
    __syncthreads();
    const unsigned int cutr = s_cut;

    // ---- ballot-ranked private-segment gather (proven r3 structure) ----
    const int idx = kb * 256 + tid;                       // batch-local anchor
    const unsigned int bits = __float_as_uint(scores[(size_t)b * NANCH + idx]);
    const bool pass = (bits >> 16) >= cutr;
    const u64 m = __ballot(pass);
    if (lane == 0) s_wcnt[w] = (unsigned int)__popcll(m);
    __syncthreads();
    unsigned int pre = 0, tot = 0;
#pragma unroll
    for (int i = 0; i < 4; ++i) { unsigned int c = s_wcnt[i]; if (i < w) pre += c; tot += c; }
    if (pass) {
        unsigned int rank = pre + (unsigned int)__popcll(m & ((1ull << lane) - 1ull));
        cand[((size_t)b * SEGS + kb) * 256 + rank] =
            ((u64)bits << 32) | (unsigned int)(~idx);
    }
    if (tid == 0) counts[b * SEGS + kb] = tot;
}

// ---- K3: counting-sort rank + decode; sfx built in LDS from raw hist --------
__global__ __launch_bounds__(1024) void k_rankdec(
        const u64* __restrict__ cand, const unsigned int* __restrict__ counts,
        const unsigned int* __restrict__ hist,
        const float* __restrict__ deltas, const float* __restrict__ anchors,
        float4* __restrict__ pre_boxes, float* __restrict__ pre_scores) {
    const int b = blockIdx.x;
    const int tid = threadIdx.x;
    const int lane = tid & 63, wid = tid >> 6;
    __shared__ u64 grouped[CAND_CAP];         // 32KB
    __shared__ unsigned int cursor[CAND_CAP]; // 16KB
    __shared__ unsigned int sfx_lds[SHBIN];   // 2KB
    __shared__ unsigned int s_ws8[8];
    for (int i = tid; i < CAND_CAP; i += 1024) { grouped[i] = 0ull; cursor[i] = 0u; }

    // ---- inline sfx: first 512 threads, one bin each (tid 0 = top bin) ----
    unsigned int c = (tid < SHBIN) ? hist[(size_t)b * SHBIN + (SHBIN - 1 - tid)] : 0u;
    unsigned int inc = c;
#pragma unroll
    for (int d = 1; d < 64; d <<= 1) {
        unsigned int v = __shfl_up(inc, d);
        if (lane >= d) inc += v;
    }
    if (lane == 63 && wid < 8) s_ws8[wid] = inc;
    __syncthreads();   // covers zero-fill + s_ws8
    if (tid < SHBIN) {
        unsigned int woff = 0;
#pragma unroll
        for (int i = 0; i < 8; ++i) if (i < wid) woff += s_ws8[i];
        sfx_lds[SHBIN - 1 - tid] = woff + inc - c;   // keys strictly above bin
    }
    __syncthreads();

    // ---- placement: 192 threads walk their segment ----
    if (tid < SEGS) {
        unsigned int v = counts[b * SEGS + tid];
        const u64* seg = cand + ((size_t)b * SEGS + tid) * 256;
        for (unsigned int k = 0; k < v; ++k) {
            u64 key = seg[k];
            unsigned int bin = (unsigned int)(key >> 48) - SH_BASE;
            unsigned int g0 = sfx_lds[bin];            // group base < n
            unsigned int slot = g0 + atomicAdd(&cursor[g0], 1u);
            if (slot < CAND_CAP) grouped[slot] = key;
        }
    }
    __syncthreads();

    // ---- rank + decode (keys never 0: score>0 and ~idx!=0) ----
    for (int p = tid; p < CAND_CAP; p += 1024) {
        u64 key = grouped[p];
        if (key == 0ull) continue;
        unsigned int bin = (unsigned int)(key >> 48) - SH_BASE;
        unsigned int g0 = sfx_lds[bin];
        unsigned int cg = cursor[g0];
        unsigned int rank = g0;
        unsigned int qe = g0 + cg; if (qe > CAND_CAP) qe = CAND_CAP;
        for (unsigned int q = g0; q < qe; ++q) rank += (grouped[q] > key);
        if (rank < PRE_K) {
            int idx = (int)(~(unsigned int)key);
            float score = __uint_as_float((unsigned int)(key >> 32));
            const float* anc = anchors + (size_t)idx * 4;
            const float* del = deltas + ((size_t)b * NANCH + idx) * 4;
            float a0 = anc[0], a1 = anc[1], a2 = anc[2], a3 = anc[3];
            float ah = a2 - a0, aw = a3 - a1;
            float acy = a0 + 0.5f * ah, acx = a1 + 0.5f * aw;
            float d0 = del[0] * 0.1f, d1 = del[1] * 0.1f;
            float d2 = del[2] * 0.2f, d3 = del[3] * 0.2f;
            float bh = expf(d2) * ah, bw = expf(d3) * aw;
            float bcy = d0 * ah + acy, bcx = d1 * aw + acx;
            float y1 = bcy - 0.5f * bh, x1 = bcx - 0.5f * bw;
            pre_boxes[(size_t)b * PRE_K + rank] = make_float4(y1, x1, y1 + bh, x1 + bw);
            pre_scores[(size_t)b * PRE_K + rank] = score;
        }
    }
}

// ---------------- K4: suppression bit-matrix, rows < RMAX_EP*64 only ---------
__global__ __launch_bounds__(64) void k_iou(const float4* __restrict__ pre_boxes,
                                            u64* __restrict__ supp) {
    const int cb = blockIdx.x;   // col word 0..31
    const int rb = blockIdx.y;   // row block 0..RMAX_EP-1
    const int b  = blockIdx.z;
    const int lane = threadIdx.x;
    const int i = rb * 64 + lane;
    const int j0 = cb * 64;
    if (cb < rb) return;
    __shared__ float4 sbox[64];
    const float4* boxes = pre_boxes + (size_t)b * PRE_K;
    int j = j0 + lane;
    sbox[lane] = (j < PRE_K) ? boxes[j] : make_float4(0.f, 0.f, 0.f, 0.f);
    __syncthreads();
    if (i >= PRE_K) return;
    float4 bi = boxes[i];
    float area_i = (bi.z - bi.x) * (bi.w - bi.y);
    u64 bits = 0ull;
    const int tmax = (PRE_K - j0 < 64) ? (PRE_K - j0) : 64;
    for (int t = 0; t < tmax; ++t) {
        int jj = j0 + t;
        if (jj <= i) continue;
        float4 bj = sbox[t];
        float iy1 = fmaxf(bi.x, bj.x), ix1 = fmaxf(bi.y, bj.y);
        float iy2 = fminf(bi.z, bj.z), ix2 = fminf(bi.w, bj.w);
        float inter = fmaxf(iy2 - iy1, 0.0f) * fmaxf(ix2 - ix1, 0.0f);
        float area_j = (bj.z - bj.x) * (bj.w - bj.y);
        float uni = area_i + area_j - inter;
        float iou = inter / fmaxf(uni, 1e-8f);
        if (iou > 0.7f) bits |= (1ull << t);
    }
    supp[((size_t)b * PRE_K + i) * 32 + cb] = bits;
}

// ---------------- K5: greedy reduce, producer/consumer multi-wave staging ----
__device__ __forceinline__ u64 readlane64(u64 x, int ln) {
    unsigned int lo = __builtin_amdgcn_readlane((unsigned int)x, ln);
    unsigned int hi = __builtin_amdgcn_readlane((unsigned int)(x >> 32), ln);
    return ((u64)hi << 32) | (u64)lo;
}

template <int ROWS>
__device__ __forceinline__ u64 proc_epoch(const u64* __restrict__ bufp, int wi,
                                          int p, int w, u64& r0, u64& r1) {
    const u64 wmask = (w >= wi) ? ~0ull : 0ull;  // unwritten words -> 0
    u64 acc = r0 | r1;
    u64 cur = ~(readlane64(acc, wi) | readlane64(acc, 32 + wi));
#pragma unroll
    for (int g = 0; g < ROWS / 16; ++g) {
        u64 ld[8];
#pragma unroll
        for (int k = 0; k < 8; ++k)
            ld[k] = bufp[(g * 16 + 2 * k + p) * 32 + w] & wmask;
        u64 t0 = (ld[0] | ld[1]) | (ld[2] | ld[3]);
        u64 t1 = (ld[4] | ld[5]) | (ld[6] | ld[7]);
        u64 tor = t0 | t1;
        u64 intra = readlane64(tor, wi) | readlane64(tor, 32 + wi);
        if (intra == 0ull) {
#pragma unroll
            for (int k = 0; k < 8; ++k) {
                int bitpos = g * 16 + 2 * k + p;
                u64 msk = ((cur >> bitpos) & 1ull) ? ~0ull : 0ull;
                if (k & 1) r1 |= ld[k] & msk; else r0 |= ld[k] & msk;
            }
        } else {
#pragma unroll
            for (int c = 0; c < 16; ++c) {
                const int pi = c & 1, k = c >> 1;
                if ((cur >> (g * 16 + c)) & 1ull) {
                    cur &= ~readlane64(ld[k], pi * 32 + wi);
                    u64 msk = (p == pi) ? ~0ull : 0ull;
                    if (k & 1) r1 |= ld[k] & msk; else r0 |= ld[k] & msk;
                }
            }
        }
    }
    return cur;
}

// inline fallback for epochs >= RMAX_EP (bit-identical IoU; rarely taken)
__device__ void fill_epoch(u64* __restrict__ dst, const float4* __restrict__ boxes,
                           int e, int l, int nthreads, int rows) {
    const int total = rows * 32;
    for (int idx = l; idx < total; idx += nthreads) {
        const int rl = idx >> 5, w = idx & 31;
        const int i = e * 64 + rl;
        const int j0 = w * 64;
        u64 bits = 0ull;
        if (i < PRE_K && j0 + 63 > i) {
            float4 bi = boxes[i];
            float area_i = (bi.z - bi.x) * (bi.w - bi.y);
            const int tmax = (PRE_K - j0 < 64) ? (PRE_K - j0) : 64;
            for (int t = 0; t < tmax; ++t) {
                int jj = j0 + t;
                if (jj <= i) continue;
                float4 bj = boxes[jj];
                float iy1 = fmaxf(bi.x, bj.x), ix1 = fmaxf(bi.y, bj.y);
                float iy2 = fminf(bi.z, bj.z), ix2 = fminf(bi.w, bj.w);
                float inter = fmaxf(iy2 - iy1, 0.0f) * fmaxf(ix2 - ix1, 0.0f);
                float area_j = (bj.z - bj.x) * (bj.w - bj.y);
                float uni = area_i + area_j - inter;
                float iou = inter / fmaxf(uni, 1e-8f);
                if (iou > 0.7f) bits |= (1ull << t);
            }
        }
        dst[idx] = bits;
    }
}

#define LDS_LD(p)  __hip_atomic_load((p), __ATOMIC_ACQUIRE, __HIP_MEMORY_SCOPE_WORKGROUP)
#define LDS_ST(p, v) __hip_atomic_store((p), (v), __ATOMIC_RELEASE, __HIP_MEMORY_SCOPE_WORKGROUP)

__global__ __launch_bounds__(512) void k_final(const u64* __restrict__ supp,
                        const float4* __restrict__ pre_boxes,
                        const float* __restrict__ pre_scores,
                        float* __restrict__ out) {
    const int b = blockIdx.x;
    const int l = threadIdx.x;
    const int wv = l >> 6;        // wave 0 = consumer; waves 1..7 = producers
    const int lw = l & 63;
    const int p = lw >> 5, w = lw & 31;
    float* ob = out + (size_t)b * POST_K * 4;
    float* os = out + (size_t)BATCH * POST_K * 4 + (size_t)b * POST_K;
    for (int t = l; t < POST_K * 4; t += 512) ob[t] = 0.0f;
    for (int t = l; t < POST_K; t += 512) os[t] = 0.0f;

    __shared__ u64 sbuf[NBUF][2048];     // 128KB epoch ring
    __shared__ int s_ready[RMAX_EP];
    __shared__ int s_consumed;
    __shared__ int s_abort;
    __shared__ int s_done;
    __shared__ int s_kept;
    if (l < RMAX_EP) s_ready[l] = 0;
    if (l == 0) { s_consumed = 0; s_abort = 0; s_done = 0; s_kept = 0; }
    __syncthreads();   // also drains the zero-fill stores (vmcnt0 before barrier)

    const char* Sb = (const char*)(supp + (size_t)b * PRE_K * 32);
    const float4* boxes = pre_boxes + (size_t)b * PRE_K;

    u64 r0 = 0ull, r1 = 0ull;
    int kept = 0;

    if (wv == 0) {
        // ---- consumer: serial greedy walk over staged epochs ----
        for (int e = 0; e < RMAX_EP; ++e) {
            while (LDS_LD(&s_ready[e]) == 0) __builtin_amdgcn_s_sleep(2);
            __builtin_amdgcn_sched_barrier(0);
            u64 curf = proc_epoch<64>(&sbuf[e % NBUF][0], e, p, w, r0, r1);
            kept += __builtin_popcountll(curf);   // wave-uniform
            LDS_ST(&s_consumed, e + 1);
            if (kept >= POST_K) break;            // exact early exit
        }
        if (lw == 0) {
            s_kept = kept;
            if (kept >= POST_K) s_done = 1;
            LDS_ST(&s_abort, 1);                  // release producers
        }
    } else {
        // ---- producers: stage every-7th epoch into the ring ----
        for (int e = wv - 1; e < RMAX_EP; e += 7) {
            bool bail = false;
            while (LDS_LD(&s_consumed) < e - (NBUF - 1)) {   // slot e%NBUF free?
                if (LDS_LD(&s_abort)) { bail = true; break; }
                __builtin_amdgcn_s_sleep(2);
            }
            if (bail || LDS_LD(&s_abort)) break;
            const char* gsrc = Sb + (size_t)e * 16384 + (size_t)lw * 16;
            char* ldst = (char*)&sbuf[e % NBUF][0];
#pragma unroll
            for (int k = 0; k < 16; ++k)
                __builtin_amdgcn_global_load_lds(
                    (const __attribute__((address_space(1))) void*)(gsrc + k * 1024),
                    (__attribute__((address_space(3))) void*)(ldst + lw * 16 + k * 1024),
                    16, 0, 0);
            asm volatile("s_waitcnt vmcnt(0)" ::: "memory");
            if (lw == 0) LDS_ST(&s_ready[e], 1);
        }
    }
    __syncthreads();
    kept = s_kept;   // broadcast (consumer's r0/r1 stay in wave 0 regs)

    // ---- fallback epochs >= RMAX_EP (uniform barriers; rarely taken) ----
    for (int e = RMAX_EP; e < 32; ++e) {
        if (s_done) break;                        // uniform: read post-barrier
        fill_epoch(&sbuf[0][0], boxes, e, l, 512, (e == 31) ? 16 : 64);
        __syncthreads();
        if (wv == 0) {
            u64 curf;
            if (e < 31) curf = proc_epoch<64>(&sbuf[0][0], e, p, w, r0, r1);
            else        curf = proc_epoch<16>(&sbuf[0][0], e, p, w, r0, r1) & 0xFFFFull;
            kept += __builtin_popcountll(curf);
            if (lw == 0 && kept >= POST_K) s_done = 1;
        }
        __syncthreads();
    }

    // ---- compact kept rows (wave 0 only; r0/r1 live there) ----
    if (wv == 0) {
        u64 full = r0 | r1;
        u64 oth = __shfl(full, w + 32);
        u64 kw = ~(full | oth);
        if (w == 31) kw &= 0xFFFFull;
        int cnt = (lw < 32) ? __builtin_popcountll(kw) : 0;
        int cum = cnt;
#pragma unroll
        for (int d = 1; d < 64; d <<= 1) {
            int v = __shfl_up(cum, d);
            if (lw >= d) cum += v;
        }
        int r = cum - cnt;
        if (lw < 32) {
            u64 m = kw;
            while (m != 0ull && r < POST_K) {
                int t = __builtin_ctzll(m);
                m &= m - 1ull;
                int i = w * 64 + t;
                float4 bx = pre_boxes[(size_t)b * PRE_K + i];
                ob[r * 4 + 0] = fminf(fmaxf(bx.x, 0.0f), 1.0f);
                ob[r * 4 + 1] = fminf(fmaxf(bx.y, 0.0f), 1.0f);
                ob[r * 4 + 2] = fminf(fmaxf(bx.z, 0.0f), 1.0f);
                ob[r * 4 + 3] = fminf(fmaxf(bx.w, 0.0f), 1.0f);
                os[r] = pre_scores[(size_t)b * PRE_K + i];
                ++r;
            }
        }
    }
}

extern "C" void kernel_launch(void* const* d_in, const int* in_sizes, int n_in,
                              void* d_out, int out_size, void* d_ws, size_t ws_size,
                              hipStream_t stream) {
    const float* deltas  = (const float*)d_in[0];
    const float* labels  = (const float*)d_in[1];
    const float* anchors = (const float*)d_in[2];
    float* out = (float*)d_out;

    char* ws = (char*)d_ws;
    float* scores          = (float*)(ws + WS_SC);
    unsigned int* hist     = (unsigned int*)(ws + WS_HIST);   // raw counts
    u64* cd                = (u64*)(ws + WS_CAND);
    unsigned int* cntp     = (unsigned int*)(ws + WS_CNT);
    float4* pre_boxes      = (float4*)(ws + WS_PB);
    float* pre_scores      = (float*)(ws + WS_PS);
    u64* sp                = (u64*)(ws + WS_SUPP);

    k_zero<<<1, 1024, 0, stream>>>((uint4*)hist);
    k_softhist<<<256, 256, 0, stream>>>(labels, scores, hist);
    k_gather<<<BATCH * SEGS, 256, 0, stream>>>(scores, hist, cd, cntp);
    k_rankdec<<<BATCH, 1024, 0, stream>>>(cd, cntp, hist, deltas, anchors,
                                          pre_boxes, pre_scores);
    k_iou<<<dim3(32, RMAX_EP, BATCH), 64, 0, stream>>>(pre_boxes, sp);
    k_final<<<BATCH, 512, 0, stream>>>(sp, pre_boxes, pre_scores, out);
}